// Round 1
// baseline (111.127 us; speedup 1.0000x reference)
//
#include <hip/hip_runtime.h>

// Problem constants (from reference): B=4096, L=50, D=400
#define BB 4096
#define LL 50
#define DD 400
#define D4 100   // D / 4 (float4 columns per row)
#define LG 5     // l-groups (5 groups x 10 rows each)
#define NT 512   // threads per block (500 active in load phase)

// The reference's two final softmaxes are over a size-1 axis => exactly 1.0.
// Hence news_att == user_att == 1, and the output collapses to:
//   score[b] = dot( LN(sum_l news[b,l,:]; g1,b1), LN(sum_l user[b,l,:]; g2,b2) )
__global__ __launch_bounds__(NT) void kim_score_kernel(
    const float* __restrict__ news, const float* __restrict__ user,
    const float* __restrict__ g1, const float* __restrict__ b1,
    const float* __restrict__ g2, const float* __restrict__ b2,
    float* __restrict__ out)
{
    const int b = blockIdx.x;
    const int t = threadIdx.x;

    __shared__ float4 sn[LG][D4];   // per-lgroup partial column sums (news)
    __shared__ float4 su[LG][D4];   // per-lgroup partial column sums (user)
    __shared__ float4 red4[128];    // block reduction scratch

    const int lg = t / D4;          // l-group 0..4 (t < 500)
    const int d4 = t - lg * D4;     // float4 column 0..99

    // ---- Phase 1: streaming column sums over L (the only HBM-heavy phase) ----
    if (t < LG * D4) {
        const float4* np4 = reinterpret_cast<const float4*>(news) + (size_t)b * (LL * D4);
        const float4* up4 = reinterpret_cast<const float4*>(user) + (size_t)b * (LL * D4);
        float4 an = make_float4(0.f, 0.f, 0.f, 0.f);
        float4 au = make_float4(0.f, 0.f, 0.f, 0.f);
        #pragma unroll
        for (int i = 0; i < LL / LG; ++i) {
            const int l = lg + i * LG;
            const float4 n = np4[l * D4 + d4];
            const float4 u = up4[l * D4 + d4];
            an.x += n.x; an.y += n.y; an.z += n.z; an.w += n.w;
            au.x += u.x; au.y += u.y; au.z += u.z; au.w += u.w;
        }
        sn[lg][d4] = an;
        su[lg][d4] = au;
    }
    __syncthreads();

    // ---- Phase 2: reduce across l-groups; per-thread stats partials ----
    float4 nsum = make_float4(0.f, 0.f, 0.f, 0.f);
    float4 usum = make_float4(0.f, 0.f, 0.f, 0.f);
    float4 part = make_float4(0.f, 0.f, 0.f, 0.f);  // {sum_n, sumsq_n, sum_u, sumsq_u}
    if (t < D4) {
        nsum = sn[0][t];
        usum = su[0][t];
        #pragma unroll
        for (int g = 1; g < LG; ++g) {
            const float4 n = sn[g][t];
            const float4 u = su[g][t];
            nsum.x += n.x; nsum.y += n.y; nsum.z += n.z; nsum.w += n.w;
            usum.x += u.x; usum.y += u.y; usum.z += u.z; usum.w += u.w;
        }
        part.x = nsum.x + nsum.y + nsum.z + nsum.w;
        part.y = nsum.x * nsum.x + nsum.y * nsum.y + nsum.z * nsum.z + nsum.w * nsum.w;
        part.z = usum.x + usum.y + usum.z + usum.w;
        part.w = usum.x * usum.x + usum.y * usum.y + usum.z * usum.z + usum.w * usum.w;
    }
    if (t < 128) red4[t] = part;  // t in [100,128) contributes zeros
    __syncthreads();

    // ---- Phase 3: block tree-reduce the 4 stats ----
    #pragma unroll
    for (int s = 64; s >= 1; s >>= 1) {
        if (t < s) {
            float4 a = red4[t];
            const float4 c = red4[t + s];
            a.x += c.x; a.y += c.y; a.z += c.z; a.w += c.w;
            red4[t] = a;
        }
        __syncthreads();
    }

    // ---- Phase 4: layernorm + dot-product partials ----
    float dp = 0.f;
    if (t < D4) {
        const float4 st = red4[0];
        const float inv = 1.f / (float)DD;
        const float mu_n = st.x * inv;
        const float var_n = st.y * inv - mu_n * mu_n;
        const float rn = rsqrtf(var_n + 1e-5f);
        const float mu_u = st.z * inv;
        const float var_u = st.w * inv - mu_u * mu_u;
        const float ru = rsqrtf(var_u + 1e-5f);
        const int d = t * 4;
        float nv, uv;
        nv = (nsum.x - mu_n) * rn * g1[d + 0] + b1[d + 0];
        uv = (usum.x - mu_u) * ru * g2[d + 0] + b2[d + 0];
        dp += nv * uv;
        nv = (nsum.y - mu_n) * rn * g1[d + 1] + b1[d + 1];
        uv = (usum.y - mu_u) * ru * g2[d + 1] + b2[d + 1];
        dp += nv * uv;
        nv = (nsum.z - mu_n) * rn * g1[d + 2] + b1[d + 2];
        uv = (usum.z - mu_u) * ru * g2[d + 2] + b2[d + 2];
        dp += nv * uv;
        nv = (nsum.w - mu_n) * rn * g1[d + 3] + b1[d + 3];
        uv = (usum.w - mu_u) * ru * g2[d + 3] + b2[d + 3];
        dp += nv * uv;
    }
    __syncthreads();  // all reads of red4[0] are done above
    if (t < 128) red4[t].x = dp;
    __syncthreads();
    #pragma unroll
    for (int s = 64; s >= 1; s >>= 1) {
        if (t < s) red4[t].x += red4[t + s].x;
        __syncthreads();
    }
    if (t == 0) out[b] = red4[0].x;
}

extern "C" void kernel_launch(void* const* d_in, const int* in_sizes, int n_in,
                              void* d_out, int out_size, void* d_ws, size_t ws_size,
                              hipStream_t stream) {
    // setup_inputs() order:
    //  0 news_vecs [B,L,D]   1 user_vecs [B,L,D]
    //  2 Wn1  3 bn1  4 Wn2  5 bn2  6 Wu1  7 bu1  8 Wu2  9 bu2  (all dead code)
    // 10 Wc  11 bc  (dead code)
    // 12 gamma1 [D] 13 beta1 [D] 14 gamma2 [D] 15 beta2 [D]
    const float* news = (const float*)d_in[0];
    const float* user = (const float*)d_in[1];
    const float* g1   = (const float*)d_in[12];
    const float* b1   = (const float*)d_in[13];
    const float* g2   = (const float*)d_in[14];
    const float* b2   = (const float*)d_in[15];
    float* out = (float*)d_out;

    kim_score_kernel<<<BB, NT, 0, stream>>>(news, user, g1, b1, g2, b2, out);
}

// Round 3
// 98.828 us; speedup vs baseline: 1.1245x; 1.1245x over previous
//
#include <hip/hip_runtime.h>

// Problem constants (from reference): B=4096, L=50, D=400
#define BB 4096
#define LL 50
#define DD 400
#define D4 100   // D / 4 (float4 columns per row)
#define LG 5     // l-groups (5 groups x 10 rows each)
#define NT 512   // threads per block (500 active in load phase)

typedef float f4 __attribute__((ext_vector_type(4)));  // clang-native vec for nontemporal builtin

// The reference's two final softmaxes are over a size-1 axis => exactly 1.0.
// Hence news_att == user_att == 1, and the output collapses to:
//   score[b] = dot( LN(sum_l news[b,l,:]; g1,b1), LN(sum_l user[b,l,:]; g2,b2) )
//
// Memory-bound: 655 MB streamed once. Inputs have zero reuse -> non-temporal
// loads to skip cache allocation on the streaming path.
__global__ __launch_bounds__(NT, 2) void kim_score_kernel(
    const float* __restrict__ news, const float* __restrict__ user,
    const float* __restrict__ g1, const float* __restrict__ b1,
    const float* __restrict__ g2, const float* __restrict__ b2,
    float* __restrict__ out)
{
    const int b = blockIdx.x;
    const int t = threadIdx.x;

    __shared__ f4 sn[LG][D4];   // per-lgroup partial column sums (news)
    __shared__ f4 su[LG][D4];   // per-lgroup partial column sums (user)
    __shared__ f4 red4[128];    // block reduction scratch

    const int lg = t / D4;          // l-group 0..4 (t < 500)
    const int d4 = t - lg * D4;     // float4 column 0..99

    // ---- Phase 1: streaming column sums over L (the only HBM-heavy phase) ----
    if (t < LG * D4) {
        const f4* np4 = reinterpret_cast<const f4*>(news) + (size_t)b * (LL * D4);
        const f4* up4 = reinterpret_cast<const f4*>(user) + (size_t)b * (LL * D4);
        f4 an = {0.f, 0.f, 0.f, 0.f};
        f4 au = {0.f, 0.f, 0.f, 0.f};
        #pragma unroll
        for (int i = 0; i < LL / LG; ++i) {
            const int l = lg + i * LG;
            const f4 n = __builtin_nontemporal_load(&np4[l * D4 + d4]);
            const f4 u = __builtin_nontemporal_load(&up4[l * D4 + d4]);
            an += n;
            au += u;
        }
        sn[lg][d4] = an;
        su[lg][d4] = au;
    }
    __syncthreads();

    // ---- Phase 2: reduce across l-groups; per-thread stats partials ----
    f4 nsum = {0.f, 0.f, 0.f, 0.f};
    f4 usum = {0.f, 0.f, 0.f, 0.f};
    f4 part = {0.f, 0.f, 0.f, 0.f};  // {sum_n, sumsq_n, sum_u, sumsq_u}
    if (t < D4) {
        nsum = sn[0][t];
        usum = su[0][t];
        #pragma unroll
        for (int g = 1; g < LG; ++g) {
            nsum += sn[g][t];
            usum += su[g][t];
        }
        part.x = nsum.x + nsum.y + nsum.z + nsum.w;
        part.y = nsum.x * nsum.x + nsum.y * nsum.y + nsum.z * nsum.z + nsum.w * nsum.w;
        part.z = usum.x + usum.y + usum.z + usum.w;
        part.w = usum.x * usum.x + usum.y * usum.y + usum.z * usum.z + usum.w * usum.w;
    }
    if (t < 128) red4[t] = part;  // t in [100,128) contributes zeros
    __syncthreads();

    // ---- Phase 3: block tree-reduce the 4 stats ----
    #pragma unroll
    for (int s = 64; s >= 1; s >>= 1) {
        if (t < s) {
            red4[t] += red4[t + s];
        }
        __syncthreads();
    }

    // ---- Phase 4: layernorm + dot-product partials ----
    float dp = 0.f;
    if (t < D4) {
        const f4 st = red4[0];
        const float inv = 1.f / (float)DD;
        const float mu_n = st.x * inv;
        const float var_n = st.y * inv - mu_n * mu_n;
        const float rn = rsqrtf(var_n + 1e-5f);
        const float mu_u = st.z * inv;
        const float var_u = st.w * inv - mu_u * mu_u;
        const float ru = rsqrtf(var_u + 1e-5f);
        const int d = t * 4;
        float nv, uv;
        nv = (nsum.x - mu_n) * rn * g1[d + 0] + b1[d + 0];
        uv = (usum.x - mu_u) * ru * g2[d + 0] + b2[d + 0];
        dp += nv * uv;
        nv = (nsum.y - mu_n) * rn * g1[d + 1] + b1[d + 1];
        uv = (usum.y - mu_u) * ru * g2[d + 1] + b2[d + 1];
        dp += nv * uv;
        nv = (nsum.z - mu_n) * rn * g1[d + 2] + b1[d + 2];
        uv = (usum.z - mu_u) * ru * g2[d + 2] + b2[d + 2];
        dp += nv * uv;
        nv = (nsum.w - mu_n) * rn * g1[d + 3] + b1[d + 3];
        uv = (usum.w - mu_u) * ru * g2[d + 3] + b2[d + 3];
        dp += nv * uv;
    }
    __syncthreads();  // all reads of red4[0] are done above
    if (t < 128) red4[t].x = dp;
    __syncthreads();
    #pragma unroll
    for (int s = 64; s >= 1; s >>= 1) {
        if (t < s) red4[t].x += red4[t + s].x;
        __syncthreads();
    }
    if (t == 0) out[b] = red4[0].x;
}

extern "C" void kernel_launch(void* const* d_in, const int* in_sizes, int n_in,
                              void* d_out, int out_size, void* d_ws, size_t ws_size,
                              hipStream_t stream) {
    // setup_inputs() order:
    //  0 news_vecs [B,L,D]   1 user_vecs [B,L,D]
    //  2 Wn1  3 bn1  4 Wn2  5 bn2  6 Wu1  7 bu1  8 Wu2  9 bu2  (all dead code)
    // 10 Wc  11 bc  (dead code)
    // 12 gamma1 [D] 13 beta1 [D] 14 gamma2 [D] 15 beta2 [D]
    const float* news = (const float*)d_in[0];
    const float* user = (const float*)d_in[1];
    const float* g1   = (const float*)d_in[12];
    const float* b1   = (const float*)d_in[13];
    const float* g2   = (const float*)d_in[14];
    const float* b2   = (const float*)d_in[15];
    float* out = (float*)d_out;

    kim_score_kernel<<<BB, NT, 0, stream>>>(news, user, g1, b1, g2, b2, out);
}